// Round 7
// baseline (336.173 us; speedup 1.0000x reference)
//
#include <hip/hip_runtime.h>

#define N_NODES   50000
#define N_EDGES   800000
#define IN_CH     128
#define HID       64
#define N_GRAPHS  64
#define N_CLASSES 2
#define NBLK_SCAN ((N_NODES + 255) / 256)   // 196

// Round 3: single-block scan was 133 us -> 3-phase scan.
// Round 4: pool_kernel 59 us at 2.3% occupancy -> atomic partial pool + finalize.
// Round 5: fill_kernel 54 us (16x write amplification) -> XCD-partitioned fill.
// Round 6: top-5 = harness ws-poison fills (43 us, fixed cost). All our kernels
// < 43 us. h2 is consumed ONLY by pool -> fuse agg2+pool1, never materialize h2
// (saves 12.8 MB write + 12.8 MB read + 1 dispatch).

// ---------------------------------------------------------------------------
// K0: in-degree count (real edges only; self-loop handled analytically)
// ---------------------------------------------------------------------------
__global__ void deg_kernel(const int* __restrict__ ei, int* __restrict__ degCount) {
    int e = blockIdx.x * blockDim.x + threadIdx.x;
    if (e < N_EDGES) {
        int dst = ei[N_EDGES + e];
        atomicAdd(&degCount[dst], 1);
    }
}

// ---------------------------------------------------------------------------
// K1a: per-256-chunk sums
// ---------------------------------------------------------------------------
__global__ __launch_bounds__(256) void scan1_kernel(const int* __restrict__ degCount,
                                                    int* __restrict__ blockSums) {
    __shared__ int red[256];
    int i = blockIdx.x * 256 + threadIdx.x;
    red[threadIdx.x] = (i < N_NODES) ? degCount[i] : 0;
    __syncthreads();
    for (int off = 128; off > 0; off >>= 1) {
        if (threadIdx.x < off) red[threadIdx.x] += red[threadIdx.x + off];
        __syncthreads();
    }
    if (threadIdx.x == 0) blockSums[blockIdx.x] = red[0];
}

// ---------------------------------------------------------------------------
// K1b: single-block exclusive scan over the 196 block sums
// ---------------------------------------------------------------------------
__global__ __launch_bounds__(256) void scan2_kernel(int* __restrict__ blockSums) {
    __shared__ int s[256];
    int t = threadIdx.x;
    int v = (t < NBLK_SCAN) ? blockSums[t] : 0;
    s[t] = v;
    __syncthreads();
    for (int off = 1; off < 256; off <<= 1) {
        int a = (t >= off) ? s[t - off] : 0;
        __syncthreads();
        s[t] += a;
        __syncthreads();
    }
    if (t < NBLK_SCAN) blockSums[t] = s[t] - v;   // exclusive prefix
}

// ---------------------------------------------------------------------------
// K1c: per-chunk exclusive scan + block offset -> rowPtr, fillPtr (aliased
//      onto degCount), dinv = (deg+1)^-0.5
// ---------------------------------------------------------------------------
__global__ __launch_bounds__(256) void scan3_kernel(int* __restrict__ degFill,
                                                    const int* __restrict__ blockSums,
                                                    int* __restrict__ rowPtr,
                                                    float* __restrict__ dinv) {
    __shared__ int s[256];
    int t = threadIdx.x;
    int i = blockIdx.x * 256 + t;
    int d = (i < N_NODES) ? degFill[i] : 0;
    s[t] = d;
    __syncthreads();
    for (int off = 1; off < 256; off <<= 1) {
        int a = (t >= off) ? s[t - off] : 0;
        __syncthreads();
        s[t] += a;
        __syncthreads();
    }
    int excl = s[t] - d + blockSums[blockIdx.x];
    if (i < N_NODES) {
        rowPtr[i]  = excl;
        degFill[i] = excl;
        dinv[i]    = 1.0f / sqrtf((float)(d + 1));
    }
    if (i == 0) rowPtr[N_NODES] = N_EDGES;        // all edges retained
}

// ---------------------------------------------------------------------------
// K2: CSR fill, XCD-partitioned + dst-windowed (round-5 fix).
// ---------------------------------------------------------------------------
#define FILL_CHUNKS ((N_EDGES + 2047) / 2048)     // 391
__global__ __launch_bounds__(256) void fill_kernel(const int* __restrict__ ei,
                                                   int* __restrict__ fillPtr,
                                                   int* __restrict__ colIdx) {
    int part = blockIdx.x & 7;
    int blk  = blockIdx.x >> 3;                   // 0..390
    int lo   = part * 6250;
    int hi   = lo + 6250;
#pragma unroll
    for (int it = 0; it < 8; ++it) {
        int e = blk * 2048 + it * 256 + (int)threadIdx.x;
        if (e < N_EDGES) {
            int dst = ei[N_EDGES + e];
            if (dst >= lo && dst < hi) {
                int src = ei[e];
                int pos = atomicAdd(&fillPtr[dst], 1);
                colIdx[pos] = src;
            }
        }
    }
}

// ---------------------------------------------------------------------------
// K3/K5: g = (A @ W) * dinv[row]     A:[N,K]  W:[K,64]  g:[N,64]
// ---------------------------------------------------------------------------
#define FMA4(xs, w, a) { (a).x = fmaf((xs), (w).x, (a).x); \
                         (a).y = fmaf((xs), (w).y, (a).y); \
                         (a).z = fmaf((xs), (w).z, (a).z); \
                         (a).w = fmaf((xs), (w).w, (a).w); }

template <int K>
__global__ __launch_bounds__(256) void gemm_kernel(const float* __restrict__ A,
                                                   const float* __restrict__ W,
                                                   const float* __restrict__ dinv,
                                                   float* __restrict__ out) {
    __shared__ float4 Ws[K * 16];                 // [K][64] floats as float4[16]
    for (int i = threadIdx.x; i < K * 16; i += 256)
        Ws[i] = ((const float4*)W)[i];
    __syncthreads();

    const int c4   = threadIdx.x & 15;
    const int rg   = threadIdx.x >> 4;            // 0..15
    const int row0 = blockIdx.x * 128 + rg * 8;

    const float4* ap[8];
#pragma unroll
    for (int r = 0; r < 8; ++r) {
        int rowc = min(row0 + r, N_NODES - 1);    // clamp: OOB rows load row N-1
        ap[r] = (const float4*)(A + (size_t)rowc * K);
    }

    float4 acc[8] = {};
    for (int kk = 0; kk < K / 4; ++kk) {
        float4 xv[8];
#pragma unroll
        for (int r = 0; r < 8; ++r) xv[r] = ap[r][kk];
        float4 w;
        w = Ws[(4 * kk + 0) * 16 + c4];
#pragma unroll
        for (int r = 0; r < 8; ++r) FMA4(xv[r].x, w, acc[r]);
        w = Ws[(4 * kk + 1) * 16 + c4];
#pragma unroll
        for (int r = 0; r < 8; ++r) FMA4(xv[r].y, w, acc[r]);
        w = Ws[(4 * kk + 2) * 16 + c4];
#pragma unroll
        for (int r = 0; r < 8; ++r) FMA4(xv[r].z, w, acc[r]);
        w = Ws[(4 * kk + 3) * 16 + c4];
#pragma unroll
        for (int r = 0; r < 8; ++r) FMA4(xv[r].w, w, acc[r]);
    }

#pragma unroll
    for (int r = 0; r < 8; ++r) {
        int row = row0 + r;
        if (row < N_NODES) {
            float dv = dinv[row];
            float4 o = acc[r];
            o.x *= dv; o.y *= dv; o.z *= dv; o.w *= dv;
            ((float4*)(out + (size_t)row * HID))[c4] = o;
        }
    }
}

// ---------------------------------------------------------------------------
// K4: layer-1 aggregation. One wave per node, lane = channel.
// out[v] = relu(dinv[v] * (g[v] + sum_{u->v} g[u]) + bias)
// ---------------------------------------------------------------------------
__global__ __launch_bounds__(256) void agg_kernel(const float* __restrict__ g,
                                                  const float* __restrict__ dinv,
                                                  const int* __restrict__ rowPtr,
                                                  const int* __restrict__ colIdx,
                                                  const float* __restrict__ bias,
                                                  float* __restrict__ out) {
    int lane = threadIdx.x & 63;
    int v = blockIdx.x * 4 + (threadIdx.x >> 6);
    if (v >= N_NODES) return;

    float acc = g[(size_t)v * HID + lane];
    int e  = rowPtr[v];
    int e1 = rowPtr[v + 1];
    for (; e + 3 < e1; e += 4) {
        int u0 = colIdx[e], u1 = colIdx[e + 1], u2 = colIdx[e + 2], u3 = colIdx[e + 3];
        float a0 = g[(size_t)u0 * HID + lane];
        float a1 = g[(size_t)u1 * HID + lane];
        float a2 = g[(size_t)u2 * HID + lane];
        float a3 = g[(size_t)u3 * HID + lane];
        acc += (a0 + a1) + (a2 + a3);
    }
    for (; e < e1; ++e) acc += g[(size_t)colIdx[e] * HID + lane];

    float r = dinv[v] * acc + bias[lane];
    out[(size_t)v * HID + lane] = fmaxf(r, 0.f);
}

// ---------------------------------------------------------------------------
// K6: layer-2 aggregation FUSED with mean-pool accumulation. h2 is consumed
// only by the pool, so never materialize it: compute the row in registers and
// atomicAdd into pooledSum[batch[v]]. ~3.2M atomics over 4096 addresses spread
// across the kernel lifetime -> negligible contention.
// ---------------------------------------------------------------------------
__global__ __launch_bounds__(256) void agg2pool_kernel(const float* __restrict__ g,
                                                       const float* __restrict__ dinv,
                                                       const int* __restrict__ rowPtr,
                                                       const int* __restrict__ colIdx,
                                                       const float* __restrict__ bias,
                                                       const int* __restrict__ batch,
                                                       float* __restrict__ pooledSum) {
    int lane = threadIdx.x & 63;
    int v = blockIdx.x * 4 + (threadIdx.x >> 6);
    if (v >= N_NODES) return;

    float acc = g[(size_t)v * HID + lane];
    int e  = rowPtr[v];
    int e1 = rowPtr[v + 1];
    for (; e + 3 < e1; e += 4) {
        int u0 = colIdx[e], u1 = colIdx[e + 1], u2 = colIdx[e + 2], u3 = colIdx[e + 3];
        float a0 = g[(size_t)u0 * HID + lane];
        float a1 = g[(size_t)u1 * HID + lane];
        float a2 = g[(size_t)u2 * HID + lane];
        float a3 = g[(size_t)u3 * HID + lane];
        acc += (a0 + a1) + (a2 + a3);
    }
    for (; e < e1; ++e) acc += g[(size_t)colIdx[e] * HID + lane];

    float r = fmaxf(dinv[v] * acc + bias[lane], 0.f);
    int gid = batch[v];                           // wave-uniform
    atomicAdd(&pooledSum[gid * HID + lane], r);
}

// ---------------------------------------------------------------------------
// K7: finalize. Block = one graph, 64 threads (lane = channel).
// d_out layout: [ out (64x2) | pooled (64x64) ]
// ---------------------------------------------------------------------------
__global__ __launch_bounds__(64) void pool2_kernel(const float* __restrict__ pooledSum,
                                                   const int* __restrict__ batch,
                                                   const float* __restrict__ Wl,
                                                   const float* __restrict__ bl,
                                                   float* __restrict__ dout) {
    int g    = blockIdx.x;
    int lane = threadIdx.x;

    int lo0 = 0, hi = N_NODES;
    while (lo0 < hi) { int mid = (lo0 + hi) >> 1; if (batch[mid] < g) lo0 = mid + 1; else hi = mid; }
    int lo1 = lo0; hi = N_NODES;
    while (lo1 < hi) { int mid = (lo1 + hi) >> 1; if (batch[mid] < g + 1) lo1 = mid + 1; else hi = mid; }
    float cnt = (float)(lo1 - lo0);

    float p = pooledSum[g * HID + lane] / fmaxf(cnt, 1.0f);
    dout[N_GRAPHS * N_CLASSES + g * HID + lane] = p;

    float p0 = p * Wl[lane * N_CLASSES + 0];
    float p1 = p * Wl[lane * N_CLASSES + 1];
#pragma unroll
    for (int off = 32; off > 0; off >>= 1) {
        p0 += __shfl_down(p0, off, 64);
        p1 += __shfl_down(p1, off, 64);
    }
    if (lane == 0) {
        dout[g * N_CLASSES + 0] = p0 + bl[0];
        dout[g * N_CLASSES + 1] = p1 + bl[1];
    }
}

// ---------------------------------------------------------------------------
extern "C" void kernel_launch(void* const* d_in, const int* in_sizes, int n_in,
                              void* d_out, int out_size, void* d_ws, size_t ws_size,
                              hipStream_t stream) {
    const float* x     = (const float*)d_in[0];
    const int*   ei    = (const int*)d_in[1];    // int32 on device
    const int*   batch = (const int*)d_in[2];    // int32 on device
    const float* W1    = (const float*)d_in[3];
    const float* b1    = (const float*)d_in[4];
    const float* W2    = (const float*)d_in[5];
    const float* b2    = (const float*)d_in[6];
    const float* Wl    = (const float*)d_in[7];
    const float* bl    = (const float*)d_in[8];
    float* out = (float*)d_out;

    char* ws = (char*)d_ws;
    size_t off = 0;
    auto alloc = [&](size_t bytes) -> void* {
        void* p = ws + off;
        off += (bytes + 255) & ~(size_t)255;
        return p;
    };
    int*   degFill   = (int*)  alloc((size_t)N_NODES * 4);        // counts -> fillPtr
    int*   rowPtr    = (int*)  alloc((size_t)(N_NODES + 1) * 4);
    float* dinv      = (float*)alloc((size_t)N_NODES * 4);
    int*   blockSums = (int*)  alloc((size_t)NBLK_SCAN * 4);
    float* pooledSum = (float*)alloc((size_t)N_GRAPHS * HID * 4);
    int*   colIdx    = (int*)  alloc((size_t)N_EDGES * 4);
    float* bufA      = (float*)alloc((size_t)N_NODES * HID * 4);  // g1, then g2
    float* bufB      = (float*)alloc((size_t)N_NODES * HID * 4);  // h1

    hipMemsetAsync(degFill, 0, (size_t)N_NODES * 4, stream);
    hipMemsetAsync(pooledSum, 0, (size_t)N_GRAPHS * HID * 4, stream);

    deg_kernel  <<<(N_EDGES + 255) / 256, 256, 0, stream>>>(ei, degFill);
    scan1_kernel<<<NBLK_SCAN, 256, 0, stream>>>(degFill, blockSums);
    scan2_kernel<<<1, 256, 0, stream>>>(blockSums);
    scan3_kernel<<<NBLK_SCAN, 256, 0, stream>>>(degFill, blockSums, rowPtr, dinv);
    fill_kernel <<<FILL_CHUNKS * 8, 256, 0, stream>>>(ei, degFill, colIdx);

    // layer 1: g1 = (x@W1)*dinv ; h1 = relu(dinv*(g1[v]+sum g1[u]) + b1)
    gemm_kernel<IN_CH><<<(N_NODES + 127) / 128, 256, 0, stream>>>(x, W1, dinv, bufA);
    agg_kernel        <<<N_NODES / 4, 256, 0, stream>>>(bufA, dinv, rowPtr, colIdx, b1, bufB);

    // layer 2: g2 = (h1@W2)*dinv ; h2 row computed in-register, pooled directly
    gemm_kernel<HID>  <<<(N_NODES + 127) / 128, 256, 0, stream>>>(bufB, W2, dinv, bufA);
    agg2pool_kernel   <<<N_NODES / 4, 256, 0, stream>>>(bufA, dinv, rowPtr, colIdx, b2, batch, pooledSum);

    // finalize pool + head
    pool2_kernel<<<N_GRAPHS, 64, 0, stream>>>(pooledSum, batch, Wl, bl, out);
}

// Round 8
// 302.618 us; speedup vs baseline: 1.1109x; 1.1109x over previous
//
#include <hip/hip_runtime.h>

#define N_NODES   50000
#define N_EDGES   800000
#define IN_CH     128
#define HID       64
#define N_GRAPHS  64
#define N_CLASSES 2
#define NBLK_SCAN ((N_NODES + 255) / 256)   // 196
#define NREP      32                        // pooledSum replicas

// Round 3: single-block scan 133us -> 3-phase scan.
// Round 4: pool 59us @2.3% occupancy -> atomic partial pool + finalize.
// Round 5: fill 54us (16x write amplification) -> XCD-partitioned fill.
// Round 6: fuse agg2+pool (h2 never materialized).
// Round 7: fusion REGRESSED (+30us): 3.2M atomics on a 16KB region = ~12.5k
// serialized RMW per 64B line at the coherence point. Fix: 32 replicas of
// pooledSum (512KB), ~390 RMW/line. Also: XCD-window deg_kernel (same
// mechanism as round-5 fill fix).

// ---------------------------------------------------------------------------
// K0: in-degree count, XCD-partitioned + dst-windowed.
// ---------------------------------------------------------------------------
#define FILL_CHUNKS ((N_EDGES + 2047) / 2048)     // 391
__global__ __launch_bounds__(256) void deg_kernel(const int* __restrict__ ei,
                                                  int* __restrict__ degCount) {
    int part = blockIdx.x & 7;
    int blk  = blockIdx.x >> 3;                   // 0..390
    int lo   = part * 6250;
    int hi   = lo + 6250;
#pragma unroll
    for (int it = 0; it < 8; ++it) {
        int e = blk * 2048 + it * 256 + (int)threadIdx.x;
        if (e < N_EDGES) {
            int dst = ei[N_EDGES + e];
            if (dst >= lo && dst < hi) atomicAdd(&degCount[dst], 1);
        }
    }
}

// ---------------------------------------------------------------------------
// K1a: per-256-chunk sums
// ---------------------------------------------------------------------------
__global__ __launch_bounds__(256) void scan1_kernel(const int* __restrict__ degCount,
                                                    int* __restrict__ blockSums) {
    __shared__ int red[256];
    int i = blockIdx.x * 256 + threadIdx.x;
    red[threadIdx.x] = (i < N_NODES) ? degCount[i] : 0;
    __syncthreads();
    for (int off = 128; off > 0; off >>= 1) {
        if (threadIdx.x < off) red[threadIdx.x] += red[threadIdx.x + off];
        __syncthreads();
    }
    if (threadIdx.x == 0) blockSums[blockIdx.x] = red[0];
}

// ---------------------------------------------------------------------------
// K1b: single-block exclusive scan over the 196 block sums
// ---------------------------------------------------------------------------
__global__ __launch_bounds__(256) void scan2_kernel(int* __restrict__ blockSums) {
    __shared__ int s[256];
    int t = threadIdx.x;
    int v = (t < NBLK_SCAN) ? blockSums[t] : 0;
    s[t] = v;
    __syncthreads();
    for (int off = 1; off < 256; off <<= 1) {
        int a = (t >= off) ? s[t - off] : 0;
        __syncthreads();
        s[t] += a;
        __syncthreads();
    }
    if (t < NBLK_SCAN) blockSums[t] = s[t] - v;   // exclusive prefix
}

// ---------------------------------------------------------------------------
// K1c: per-chunk exclusive scan + block offset -> rowPtr, fillPtr (aliased
//      onto degCount), dinv = (deg+1)^-0.5
// ---------------------------------------------------------------------------
__global__ __launch_bounds__(256) void scan3_kernel(int* __restrict__ degFill,
                                                    const int* __restrict__ blockSums,
                                                    int* __restrict__ rowPtr,
                                                    float* __restrict__ dinv) {
    __shared__ int s[256];
    int t = threadIdx.x;
    int i = blockIdx.x * 256 + t;
    int d = (i < N_NODES) ? degFill[i] : 0;
    s[t] = d;
    __syncthreads();
    for (int off = 1; off < 256; off <<= 1) {
        int a = (t >= off) ? s[t - off] : 0;
        __syncthreads();
        s[t] += a;
        __syncthreads();
    }
    int excl = s[t] - d + blockSums[blockIdx.x];
    if (i < N_NODES) {
        rowPtr[i]  = excl;
        degFill[i] = excl;
        dinv[i]    = 1.0f / sqrtf((float)(d + 1));
    }
    if (i == 0) rowPtr[N_NODES] = N_EDGES;        // all edges retained
}

// ---------------------------------------------------------------------------
// K2: CSR fill, XCD-partitioned + dst-windowed (round-5 fix).
// ---------------------------------------------------------------------------
__global__ __launch_bounds__(256) void fill_kernel(const int* __restrict__ ei,
                                                   int* __restrict__ fillPtr,
                                                   int* __restrict__ colIdx) {
    int part = blockIdx.x & 7;
    int blk  = blockIdx.x >> 3;                   // 0..390
    int lo   = part * 6250;
    int hi   = lo + 6250;
#pragma unroll
    for (int it = 0; it < 8; ++it) {
        int e = blk * 2048 + it * 256 + (int)threadIdx.x;
        if (e < N_EDGES) {
            int dst = ei[N_EDGES + e];
            if (dst >= lo && dst < hi) {
                int src = ei[e];
                int pos = atomicAdd(&fillPtr[dst], 1);
                colIdx[pos] = src;
            }
        }
    }
}

// ---------------------------------------------------------------------------
// K3/K5: g = (A @ W) * dinv[row]     A:[N,K]  W:[K,64]  g:[N,64]
// ---------------------------------------------------------------------------
#define FMA4(xs, w, a) { (a).x = fmaf((xs), (w).x, (a).x); \
                         (a).y = fmaf((xs), (w).y, (a).y); \
                         (a).z = fmaf((xs), (w).z, (a).z); \
                         (a).w = fmaf((xs), (w).w, (a).w); }

template <int K>
__global__ __launch_bounds__(256) void gemm_kernel(const float* __restrict__ A,
                                                   const float* __restrict__ W,
                                                   const float* __restrict__ dinv,
                                                   float* __restrict__ out) {
    __shared__ float4 Ws[K * 16];                 // [K][64] floats as float4[16]
    for (int i = threadIdx.x; i < K * 16; i += 256)
        Ws[i] = ((const float4*)W)[i];
    __syncthreads();

    const int c4   = threadIdx.x & 15;
    const int rg   = threadIdx.x >> 4;            // 0..15
    const int row0 = blockIdx.x * 128 + rg * 8;

    const float4* ap[8];
#pragma unroll
    for (int r = 0; r < 8; ++r) {
        int rowc = min(row0 + r, N_NODES - 1);    // clamp: OOB rows load row N-1
        ap[r] = (const float4*)(A + (size_t)rowc * K);
    }

    float4 acc[8] = {};
    for (int kk = 0; kk < K / 4; ++kk) {
        float4 xv[8];
#pragma unroll
        for (int r = 0; r < 8; ++r) xv[r] = ap[r][kk];
        float4 w;
        w = Ws[(4 * kk + 0) * 16 + c4];
#pragma unroll
        for (int r = 0; r < 8; ++r) FMA4(xv[r].x, w, acc[r]);
        w = Ws[(4 * kk + 1) * 16 + c4];
#pragma unroll
        for (int r = 0; r < 8; ++r) FMA4(xv[r].y, w, acc[r]);
        w = Ws[(4 * kk + 2) * 16 + c4];
#pragma unroll
        for (int r = 0; r < 8; ++r) FMA4(xv[r].z, w, acc[r]);
        w = Ws[(4 * kk + 3) * 16 + c4];
#pragma unroll
        for (int r = 0; r < 8; ++r) FMA4(xv[r].w, w, acc[r]);
    }

#pragma unroll
    for (int r = 0; r < 8; ++r) {
        int row = row0 + r;
        if (row < N_NODES) {
            float dv = dinv[row];
            float4 o = acc[r];
            o.x *= dv; o.y *= dv; o.z *= dv; o.w *= dv;
            ((float4*)(out + (size_t)row * HID))[c4] = o;
        }
    }
}

// ---------------------------------------------------------------------------
// K4: layer-1 aggregation. One wave per node, lane = channel.
// ---------------------------------------------------------------------------
__global__ __launch_bounds__(256) void agg_kernel(const float* __restrict__ g,
                                                  const float* __restrict__ dinv,
                                                  const int* __restrict__ rowPtr,
                                                  const int* __restrict__ colIdx,
                                                  const float* __restrict__ bias,
                                                  float* __restrict__ out) {
    int lane = threadIdx.x & 63;
    int v = blockIdx.x * 4 + (threadIdx.x >> 6);
    if (v >= N_NODES) return;

    float acc = g[(size_t)v * HID + lane];
    int e  = rowPtr[v];
    int e1 = rowPtr[v + 1];
    for (; e + 3 < e1; e += 4) {
        int u0 = colIdx[e], u1 = colIdx[e + 1], u2 = colIdx[e + 2], u3 = colIdx[e + 3];
        float a0 = g[(size_t)u0 * HID + lane];
        float a1 = g[(size_t)u1 * HID + lane];
        float a2 = g[(size_t)u2 * HID + lane];
        float a3 = g[(size_t)u3 * HID + lane];
        acc += (a0 + a1) + (a2 + a3);
    }
    for (; e < e1; ++e) acc += g[(size_t)colIdx[e] * HID + lane];

    float r = dinv[v] * acc + bias[lane];
    out[(size_t)v * HID + lane] = fmaxf(r, 0.f);
}

// ---------------------------------------------------------------------------
// K6: layer-2 aggregation fused with pool accumulation, REPLICATED target:
// block's replica = blockIdx&31 -> ~390 RMW per 64B line (was 12.5k).
// ---------------------------------------------------------------------------
__global__ __launch_bounds__(256) void agg2pool_kernel(const float* __restrict__ g,
                                                       const float* __restrict__ dinv,
                                                       const int* __restrict__ rowPtr,
                                                       const int* __restrict__ colIdx,
                                                       const float* __restrict__ bias,
                                                       const int* __restrict__ batch,
                                                       float* __restrict__ pooledSum) {
    int lane = threadIdx.x & 63;
    int v = blockIdx.x * 4 + (threadIdx.x >> 6);
    if (v >= N_NODES) return;

    float acc = g[(size_t)v * HID + lane];
    int e  = rowPtr[v];
    int e1 = rowPtr[v + 1];
    for (; e + 3 < e1; e += 4) {
        int u0 = colIdx[e], u1 = colIdx[e + 1], u2 = colIdx[e + 2], u3 = colIdx[e + 3];
        float a0 = g[(size_t)u0 * HID + lane];
        float a1 = g[(size_t)u1 * HID + lane];
        float a2 = g[(size_t)u2 * HID + lane];
        float a3 = g[(size_t)u3 * HID + lane];
        acc += (a0 + a1) + (a2 + a3);
    }
    for (; e < e1; ++e) acc += g[(size_t)colIdx[e] * HID + lane];

    float r = fmaxf(dinv[v] * acc + bias[lane], 0.f);
    int gid = batch[v];                           // wave-uniform
    int rep = blockIdx.x & (NREP - 1);
    atomicAdd(&pooledSum[(size_t)rep * N_GRAPHS * HID + gid * HID + lane], r);
}

// ---------------------------------------------------------------------------
// K7: finalize. Block = one graph, 64 threads (lane = channel).
// Sums the 32 replicas, divides by count, head via shuffle reduce.
// d_out layout: [ out (64x2) | pooled (64x64) ]
// ---------------------------------------------------------------------------
__global__ __launch_bounds__(64) void pool2_kernel(const float* __restrict__ pooledSum,
                                                   const int* __restrict__ batch,
                                                   const float* __restrict__ Wl,
                                                   const float* __restrict__ bl,
                                                   float* __restrict__ dout) {
    int g    = blockIdx.x;
    int lane = threadIdx.x;

    int lo0 = 0, hi = N_NODES;
    while (lo0 < hi) { int mid = (lo0 + hi) >> 1; if (batch[mid] < g) lo0 = mid + 1; else hi = mid; }
    int lo1 = lo0; hi = N_NODES;
    while (lo1 < hi) { int mid = (lo1 + hi) >> 1; if (batch[mid] < g + 1) lo1 = mid + 1; else hi = mid; }
    float cnt = (float)(lo1 - lo0);

    float s = 0.f;
#pragma unroll
    for (int rep = 0; rep < NREP; ++rep)
        s += pooledSum[(size_t)rep * N_GRAPHS * HID + g * HID + lane];

    float p = s / fmaxf(cnt, 1.0f);
    dout[N_GRAPHS * N_CLASSES + g * HID + lane] = p;

    float p0 = p * Wl[lane * N_CLASSES + 0];
    float p1 = p * Wl[lane * N_CLASSES + 1];
#pragma unroll
    for (int off = 32; off > 0; off >>= 1) {
        p0 += __shfl_down(p0, off, 64);
        p1 += __shfl_down(p1, off, 64);
    }
    if (lane == 0) {
        dout[g * N_CLASSES + 0] = p0 + bl[0];
        dout[g * N_CLASSES + 1] = p1 + bl[1];
    }
}

// ---------------------------------------------------------------------------
extern "C" void kernel_launch(void* const* d_in, const int* in_sizes, int n_in,
                              void* d_out, int out_size, void* d_ws, size_t ws_size,
                              hipStream_t stream) {
    const float* x     = (const float*)d_in[0];
    const int*   ei    = (const int*)d_in[1];    // int32 on device
    const int*   batch = (const int*)d_in[2];    // int32 on device
    const float* W1    = (const float*)d_in[3];
    const float* b1    = (const float*)d_in[4];
    const float* W2    = (const float*)d_in[5];
    const float* b2    = (const float*)d_in[6];
    const float* Wl    = (const float*)d_in[7];
    const float* bl    = (const float*)d_in[8];
    float* out = (float*)d_out;

    char* ws = (char*)d_ws;
    size_t off = 0;
    auto alloc = [&](size_t bytes) -> void* {
        void* p = ws + off;
        off += (bytes + 255) & ~(size_t)255;
        return p;
    };
    int*   degFill   = (int*)  alloc((size_t)N_NODES * 4);        // counts -> fillPtr
    int*   rowPtr    = (int*)  alloc((size_t)(N_NODES + 1) * 4);
    float* dinv      = (float*)alloc((size_t)N_NODES * 4);
    int*   blockSums = (int*)  alloc((size_t)NBLK_SCAN * 4);
    float* pooledSum = (float*)alloc((size_t)NREP * N_GRAPHS * HID * 4);  // 512 KB
    int*   colIdx    = (int*)  alloc((size_t)N_EDGES * 4);
    float* bufA      = (float*)alloc((size_t)N_NODES * HID * 4);  // g1, then g2
    float* bufB      = (float*)alloc((size_t)N_NODES * HID * 4);  // h1

    hipMemsetAsync(degFill, 0, (size_t)N_NODES * 4, stream);
    hipMemsetAsync(pooledSum, 0, (size_t)NREP * N_GRAPHS * HID * 4, stream);

    deg_kernel  <<<FILL_CHUNKS * 8, 256, 0, stream>>>(ei, degFill);
    scan1_kernel<<<NBLK_SCAN, 256, 0, stream>>>(degFill, blockSums);
    scan2_kernel<<<1, 256, 0, stream>>>(blockSums);
    scan3_kernel<<<NBLK_SCAN, 256, 0, stream>>>(degFill, blockSums, rowPtr, dinv);
    fill_kernel <<<FILL_CHUNKS * 8, 256, 0, stream>>>(ei, degFill, colIdx);

    // layer 1: g1 = (x@W1)*dinv ; h1 = relu(dinv*(g1[v]+sum g1[u]) + b1)
    gemm_kernel<IN_CH><<<(N_NODES + 127) / 128, 256, 0, stream>>>(x, W1, dinv, bufA);
    agg_kernel        <<<N_NODES / 4, 256, 0, stream>>>(bufA, dinv, rowPtr, colIdx, b1, bufB);

    // layer 2: g2 = (h1@W2)*dinv ; h2 row computed in-register, pooled directly
    gemm_kernel<HID>  <<<(N_NODES + 127) / 128, 256, 0, stream>>>(bufB, W2, dinv, bufA);
    agg2pool_kernel   <<<N_NODES / 4, 256, 0, stream>>>(bufA, dinv, rowPtr, colIdx, b2, batch, pooledSum);

    // finalize pool + head
    pool2_kernel<<<N_GRAPHS, 64, 0, stream>>>(pooledSum, batch, Wl, bl, out);
}